// Round 1
// baseline (568.986 us; speedup 1.0000x reference)
//
#include <hip/hip_runtime.h>
#include <math.h>
#include <float.h>

#define NPTS 4096
#define ROWS_PER_BLOCK 8
#define KNN 20

// Insert (v,vi) into sorted-ascending (cc,ii); larger of the pair carries on in (v,vi).
#define INS_STAGE(cc, ii)                                        \
    { bool lt_ = (v < cc);                                       \
      float mx_ = lt_ ? cc : v;  int mi_ = lt_ ? ii : vi;        \
      cc = lt_ ? v : cc;         ii = lt_ ? vi : ii;             \
      v = mx_; vi = mi_; }

__global__ __launch_bounds__(512, 4)
void lae_kernel(const float* __restrict__ x,
                const float* __restrict__ w1, const float* __restrict__ b1,
                const float* __restrict__ w2, const float* __restrict__ b2,
                const float* __restrict__ w3, const float* __restrict__ b3,
                float* __restrict__ out)
{
    __shared__ float sx[NPTS], sy[NPTS], sz[NPTS];
    __shared__ int   s_nbr[ROWS_PER_BLOCK][KNN];
    __shared__ float s_tr[ROWS_PER_BLOCK][KNN][16];

    const int tid  = threadIdx.x;
    const int lane = tid & 63;
    const int wid  = tid >> 6;          // wave id = row within block
    const int b    = blockIdx.y;
    const int nrow = blockIdx.x * ROWS_PER_BLOCK + wid;

    // --- stage this batch's cloud into LDS (SoA), coalesced float4 ---
    const float* xb = x + (size_t)b * 3 * NPTS;
    for (int i = tid; i < NPTS / 4; i += 512) {
        float4 a = ((const float4*)(xb           ))[i];
        float4 c = ((const float4*)(xb +     NPTS))[i];
        float4 d = ((const float4*)(xb + 2 * NPTS))[i];
        ((float4*)sx)[i] = a;
        ((float4*)sy)[i] = c;
        ((float4*)sz)[i] = d;
    }
    __syncthreads();

    const float cx = sx[nrow], cy = sy[nrow], cz = sz[nrow];
    const float cxx = cx*cx + cy*cy + cz*cz;

    // d = -neg_dist, with neg_dist = (2*inner - xx_n) - xx_m  (matches ref rounding;
    // 2*inner is an exact scale so FMA contraction cannot change the value).
    auto distTo = [&](int m) -> float {
        float mx = sx[m], my = sy[m], mz = sz[m];
        float inner = cx*mx + cy*my + cz*mz;
        float mxx   = mx*mx + my*my + mz*mz;
        return mxx - (2.0f * inner - cxx);
    };

    // --- pass 1: per-lane sorted top-4 cache over this lane's 64 candidates ---
    float c0 = FLT_MAX, c1 = FLT_MAX, c2 = FLT_MAX, c3 = FLT_MAX;
    int   i0 = -1, i1 = -1, i2 = -1, i3 = -1;
    for (int j = 0; j < 64; ++j) {
        int m = (j << 6) + lane;            // strided: conflict-free LDS banks
        float v = distTo(m); int vi = m;
        INS_STAGE(c0, i0) INS_STAGE(c1, i1) INS_STAGE(c2, i2) INS_STAGE(c3, i3)
    }

    // --- extraction: 20 x { wave-min over cache heads, winner pops } ---
    int cnt = 4;
    for (int t = 0; t < KNN; ++t) {
        float g = c0;
        #pragma unroll
        for (int off = 32; off; off >>= 1) g = fminf(g, __shfl_xor(g, off));
        unsigned long long mk = __ballot(c0 == g);
        int winner = (int)__builtin_ctzll(mk);
        int mstar  = __shfl(i0, winner);
        if (lane == 0) s_nbr[wid][t] = mstar;
        if (lane == winner) {
            c0 = c1; i0 = i1; c1 = c2; i1 = i2; c2 = c3; i2 = i3;
            c3 = FLT_MAX; i3 = -1;
            cnt--;
        }
        if (cnt == 0) {   // rare refill: rebuild top-4 of this lane's range minus emitted
            c0 = c1 = c2 = c3 = FLT_MAX; i0 = i1 = i2 = i3 = -1;
            for (int j = 0; j < 64; ++j) {
                int m = (j << 6) + lane;
                bool ex = false;
                for (int e = 0; e <= t; ++e) ex = ex || (s_nbr[wid][e] == m);
                if (!ex) {
                    float v = distTo(m); int vi = m;
                    INS_STAGE(c0, i0) INS_STAGE(c1, i1) INS_STAGE(c2, i2) INS_STAGE(c3, i3)
                }
            }
            cnt = 4;
        }
    }

    // --- downstream: self-attention scalar (redundant per lane) ---
    float sa = b3[0];
    #pragma unroll
    for (int o = 0; o < 16; ++o) {
        float f = b1[o] + w1[o*3+0]*cx + w1[o*3+1]*cy + w1[o*3+2]*cz;
        sa += w3[o] * f;
    }

    // lanes 0..19 each own one neighbor
    int k = (lane < KNN) ? lane : 0;
    int m = s_nbr[wid][k];
    float dx = cx - sx[m], dy = cy - sy[m], dz = cz - sz[m];
    float x1v[16];
    float na = b3[0];
    #pragma unroll
    for (int o = 0; o < 16; ++o) {
        float t2 = b2[o] + w2[o*3+0]*dx + w2[o*3+1]*dy + w2[o*3+2]*dz;
        x1v[o] = t2;
        na += w3[o] * t2;
    }
    float logit = sa + na;
    float l = (logit >= 0.f) ? logit : 0.01f * logit;   // leaky_relu(0.01)

    float lm = (lane < KNN) ? l : -FLT_MAX;
    #pragma unroll
    for (int off = 32; off; off >>= 1) lm = fmaxf(lm, __shfl_xor(lm, off));
    float p = (lane < KNN) ? expf(l - lm) : 0.f;
    float ps = p;
    #pragma unroll
    for (int off = 32; off; off >>= 1) ps += __shfl_xor(ps, off);
    float coef = p / ps;

    if (lane < KNN) {
        #pragma unroll
        for (int o = 0; o < 16; ++o) s_tr[wid][lane][o] = coef * x1v[o];
    }
    __syncthreads();

    if (lane < 16) {
        float acc = 0.f;
        #pragma unroll
        for (int k2 = 0; k2 < KNN; ++k2) acc += s_tr[wid][k2][lane];
        float r = (acc > 0.f) ? acc : expm1f(acc);      // elu
        out[((size_t)b * 16 + lane) * NPTS + nrow] = r;
    }
}

extern "C" void kernel_launch(void* const* d_in, const int* in_sizes, int n_in,
                              void* d_out, int out_size, void* d_ws, size_t ws_size,
                              hipStream_t stream)
{
    const float* x  = (const float*)d_in[0];
    const float* w1 = (const float*)d_in[1];
    const float* b1 = (const float*)d_in[2];
    const float* w2 = (const float*)d_in[3];
    const float* b2 = (const float*)d_in[4];
    const float* w3 = (const float*)d_in[5];
    const float* b3 = (const float*)d_in[6];
    float* out = (float*)d_out;

    dim3 grid(NPTS / ROWS_PER_BLOCK, 16, 1);
    lae_kernel<<<grid, dim3(512, 1, 1), 0, stream>>>(x, w1, b1, w2, b2, w3, b3, out);
}

// Round 3
// 500.399 us; speedup vs baseline: 1.1371x; 1.1371x over previous
//
#include <hip/hip_runtime.h>
#include <math.h>
#include <float.h>

#define NPTS 4096
#define ROWS 16            // rows (= waves) per block
#define KNN 20

// ---- DPP helpers: full-wave reductions on the VALU (no DS-pipe shuffles) ----
#define ROW_SHR1   0x111
#define ROW_SHR2   0x112
#define ROW_SHR4   0x114
#define ROW_SHR8   0x118
#define ROW_BCAST15  0x142
#define ROW_BCAST31  0x143

template <int CTRL>
__device__ __forceinline__ float dpp_mv(float x, float ident) {
    int r = __builtin_amdgcn_update_dpp(__float_as_int(ident), __float_as_int(x),
                                        CTRL, 0xf, 0xf, false);
    return __int_as_float(r);
}
__device__ __forceinline__ float readlane_f(float v, int l) {
    return __int_as_float(__builtin_amdgcn_readlane(__float_as_int(v), l));
}
// returns the reduction over all 64 lanes as a wave-uniform value (via lane 63)
__device__ __forceinline__ float wave_min_bcast(float v) {
    v = fminf(v, dpp_mv<ROW_SHR1>(v, FLT_MAX));
    v = fminf(v, dpp_mv<ROW_SHR2>(v, FLT_MAX));
    v = fminf(v, dpp_mv<ROW_SHR4>(v, FLT_MAX));
    v = fminf(v, dpp_mv<ROW_SHR8>(v, FLT_MAX));
    v = fminf(v, dpp_mv<ROW_BCAST15>(v, FLT_MAX));
    v = fminf(v, dpp_mv<ROW_BCAST31>(v, FLT_MAX));
    return readlane_f(v, 63);
}
__device__ __forceinline__ float wave_max_bcast(float v) {
    v = fmaxf(v, dpp_mv<ROW_SHR1>(v, -FLT_MAX));
    v = fmaxf(v, dpp_mv<ROW_SHR2>(v, -FLT_MAX));
    v = fmaxf(v, dpp_mv<ROW_SHR4>(v, -FLT_MAX));
    v = fmaxf(v, dpp_mv<ROW_SHR8>(v, -FLT_MAX));
    v = fmaxf(v, dpp_mv<ROW_BCAST15>(v, -FLT_MAX));
    v = fmaxf(v, dpp_mv<ROW_BCAST31>(v, -FLT_MAX));
    return readlane_f(v, 63);
}
__device__ __forceinline__ float wave_sum_bcast(float v) {
    v += dpp_mv<ROW_SHR1>(v, 0.f);
    v += dpp_mv<ROW_SHR2>(v, 0.f);
    v += dpp_mv<ROW_SHR4>(v, 0.f);
    v += dpp_mv<ROW_SHR8>(v, 0.f);
    v += dpp_mv<ROW_BCAST15>(v, 0.f);
    v += dpp_mv<ROW_BCAST31>(v, 0.f);
    return readlane_f(v, 63);
}

// Insert (v,vi) into sorted-ascending (cc,ii); larger of the pair carries on.
#define INS_STAGE(cc, ii)                                        \
    { bool lt_ = (v < cc);                                       \
      float mx_ = lt_ ? cc : v;  int mi_ = lt_ ? ii : vi;        \
      cc = lt_ ? v : cc;         ii = lt_ ? vi : ii;             \
      v = mx_; vi = mi_; }

__global__ __launch_bounds__(1024, 8)
void lae_kernel(const float* __restrict__ x,
                const float* __restrict__ w1, const float* __restrict__ b1,
                const float* __restrict__ w2, const float* __restrict__ b2,
                const float* __restrict__ w3, const float* __restrict__ b3,
                float* __restrict__ out)
{
    __shared__ float sx[NPTS], sy[NPTS], sz[NPTS];
    __shared__ int   s_nbr[ROWS][KNN];
    __shared__ float s_cf[ROWS][KNN];
    __shared__ float s_tr[ROWS][KNN][17];   // pad 17: bijective bank map

    const int tid  = threadIdx.x;
    const int lane = tid & 63;
    const int wid  = tid >> 6;
    const int b    = blockIdx.y;
    const int nrow = blockIdx.x * ROWS + wid;

    // --- stage this batch's cloud into LDS (SoA), coalesced float4 ---
    const float* xb = x + (size_t)b * 3 * NPTS;
    {
        int i = tid;                         // NPTS/4 == 1024 == blockDim
        float4 a = ((const float4*)(xb           ))[i];
        float4 c = ((const float4*)(xb +     NPTS))[i];
        float4 d = ((const float4*)(xb + 2 * NPTS))[i];
        ((float4*)sx)[i] = a;
        ((float4*)sy)[i] = c;
        ((float4*)sz)[i] = d;
    }
    __syncthreads();

    const float cx = sx[nrow], cy = sy[nrow], cz = sz[nrow];
    const float cxx = cx*cx + cy*cy + cz*cz;

    // --- pass 1: per-lane sorted top-4 cache, prefetched coords ---
    float c0 = FLT_MAX, c1 = FLT_MAX, c2 = FLT_MAX, c3 = FLT_MAX;
    int   i0 = -1, i1 = -1, i2 = -1, i3 = -1;
    float nx = sx[lane], ny = sy[lane], nz = sz[lane];
    #pragma unroll 4
    for (int j = 0; j < 64; ++j) {
        const int mi = (j << 6) + lane;
        const float mx = nx, my = ny, mz = nz;
        const int mn = (mi + 64) & (NPTS - 1);   // wraps on last iter (harmless)
        nx = sx[mn]; ny = sy[mn]; nz = sz[mn];
        float inner = cx*mx + cy*my + cz*mz;
        float mxx   = mx*mx + my*my + mz*mz;
        float v = mxx - (2.0f * inner - cxx);
        int vi = mi;
        INS_STAGE(c0, i0) INS_STAGE(c1, i1) INS_STAGE(c2, i2) INS_STAGE(c3, i3)
    }

    // --- extraction: 20 x { DPP wave-min, winner pops } ---
    int cnt = 4;
    for (int t = 0; t < KNN; ++t) {
        float g = wave_min_bcast(c0);
        unsigned long long mk = __ballot(c0 == g);
        int winner = (int)__builtin_ctzll(mk);
        int mstar  = __builtin_amdgcn_readlane(i0, winner);
        if (lane == 0) s_nbr[wid][t] = mstar;
        if (lane == winner) {
            c0 = c1; i0 = i1; c1 = c2; i1 = i2; c2 = c3; i2 = i3;
            c3 = FLT_MAX; i3 = -1;
            cnt--;
        }
        if (cnt == 0) {   // rare: rebuild this lane's top-4 minus emitted
            c0 = c1 = c2 = c3 = FLT_MAX; i0 = i1 = i2 = i3 = -1;
            for (int j = 0; j < 64; ++j) {
                int m = (j << 6) + lane;
                bool ex = false;
                for (int e = 0; e <= t; ++e) ex = ex || (s_nbr[wid][e] == m);
                if (!ex) {
                    float mx = sx[m], my = sy[m], mz = sz[m];
                    float inner = cx*mx + cy*my + cz*mz;
                    float mxx   = mx*mx + my*my + mz*mz;
                    float v = mxx - (2.0f * inner - cxx);
                    int vi = m;
                    INS_STAGE(c0, i0) INS_STAGE(c1, i1) INS_STAGE(c2, i2) INS_STAGE(c3, i3)
                }
            }
            cnt = 4;
        }
    }

    // --- downstream (per wave, no block barrier needed: LDS is in-order) ---
    float sa = b3[0];
    #pragma unroll
    for (int o = 0; o < 16; ++o) {
        float f = b1[o] + w1[o*3+0]*cx + w1[o*3+1]*cy + w1[o*3+2]*cz;
        sa += w3[o] * f;
    }

    int k = (lane < KNN) ? lane : 0;
    int m = s_nbr[wid][k];
    float dx = cx - sx[m], dy = cy - sy[m], dz = cz - sz[m];
    float na = b3[0];
    #pragma unroll
    for (int o = 0; o < 16; ++o) {
        float t2 = b2[o] + w2[o*3+0]*dx + w2[o*3+1]*dy + w2[o*3+2]*dz;
        if (lane < KNN) s_tr[wid][lane][o] = t2;
        na += w3[o] * t2;
    }
    float logit = sa + na;
    float l = (logit >= 0.f) ? logit : 0.01f * logit;   // leaky_relu(0.01)

    float lm = wave_max_bcast((lane < KNN) ? l : -FLT_MAX);
    float p  = (lane < KNN) ? expf(l - lm) : 0.f;
    float ps = wave_sum_bcast(p);
    if (lane < KNN) s_cf[wid][lane] = p / ps;

    if (lane < 16) {
        float acc = 0.f;
        #pragma unroll
        for (int k2 = 0; k2 < KNN; ++k2) acc += s_cf[wid][k2] * s_tr[wid][k2][lane];
        float r = (acc > 0.f) ? acc : expm1f(acc);      // elu
        out[((size_t)b * 16 + lane) * NPTS + nrow] = r;
    }
}

extern "C" void kernel_launch(void* const* d_in, const int* in_sizes, int n_in,
                              void* d_out, int out_size, void* d_ws, size_t ws_size,
                              hipStream_t stream)
{
    const float* x  = (const float*)d_in[0];
    const float* w1 = (const float*)d_in[1];
    const float* b1 = (const float*)d_in[2];
    const float* w2 = (const float*)d_in[3];
    const float* b2 = (const float*)d_in[4];
    const float* w3 = (const float*)d_in[5];
    const float* b3 = (const float*)d_in[6];
    float* out = (float*)d_out;

    dim3 grid(NPTS / ROWS, 16, 1);
    lae_kernel<<<grid, dim3(1024, 1, 1), 0, stream>>>(x, w1, b1, w2, b2, w3, b3, out);
}

// Round 4
// 400.509 us; speedup vs baseline: 1.4207x; 1.2494x over previous
//
#include <hip/hip_runtime.h>
#include <math.h>
#include <float.h>

#define NPTS 4096
#define KNN  20
#define ROWSB 16   // rows per block (8 waves x 2 rows/wave)

#define ROW_SHR1    0x111
#define ROW_SHR2    0x112
#define ROW_SHR4    0x114
#define ROW_SHR8    0x118
#define ROW_BCAST15 0x142
#define ROW_BCAST31 0x143

template <int CTRL>
__device__ __forceinline__ float dpp_mv(float x, float ident) {
    int r = __builtin_amdgcn_update_dpp(__float_as_int(ident), __float_as_int(x),
                                        CTRL, 0xf, 0xf, false);
    return __int_as_float(r);
}
__device__ __forceinline__ float readlane_f(float v, int l) {
    return __int_as_float(__builtin_amdgcn_readlane(__float_as_int(v), l));
}
// full-wave min, broadcast via lane 63
__device__ __forceinline__ float wave_min_bcast(float v) {
    v = fminf(v, dpp_mv<ROW_SHR1>(v, FLT_MAX));
    v = fminf(v, dpp_mv<ROW_SHR2>(v, FLT_MAX));
    v = fminf(v, dpp_mv<ROW_SHR4>(v, FLT_MAX));
    v = fminf(v, dpp_mv<ROW_SHR8>(v, FLT_MAX));
    v = fminf(v, dpp_mv<ROW_BCAST15>(v, FLT_MAX));
    v = fminf(v, dpp_mv<ROW_BCAST31>(v, FLT_MAX));
    return readlane_f(v, 63);
}
// half-wave reductions: totals land at lane 31 (lower half) and lane 63 (upper half)
__device__ __forceinline__ float half_max(float v) {
    v = fmaxf(v, dpp_mv<ROW_SHR1>(v, -FLT_MAX));
    v = fmaxf(v, dpp_mv<ROW_SHR2>(v, -FLT_MAX));
    v = fmaxf(v, dpp_mv<ROW_SHR4>(v, -FLT_MAX));
    v = fmaxf(v, dpp_mv<ROW_SHR8>(v, -FLT_MAX));
    v = fmaxf(v, dpp_mv<ROW_BCAST15>(v, -FLT_MAX));
    return v;
}
__device__ __forceinline__ float half_sum(float v) {
    v += dpp_mv<ROW_SHR1>(v, 0.f);
    v += dpp_mv<ROW_SHR2>(v, 0.f);
    v += dpp_mv<ROW_SHR4>(v, 0.f);
    v += dpp_mv<ROW_SHR8>(v, 0.f);
    v += dpp_mv<ROW_BCAST15>(v, 0.f);
    return v;
}

// Insert (v,vi) into sorted-ascending cache slot; larger of pair carries on.
#define INS_STAGE(cc, ii)                                        \
    { bool lt_ = (v < cc);                                       \
      float mx_ = lt_ ? cc : v;  int mi_ = lt_ ? ii : vi;        \
      cc = lt_ ? v : cc;         ii = lt_ ? vi : ii;             \
      v = mx_; vi = mi_; }

// Rebuild a lane's top-4 over its candidate column, excluding already-emitted.
#define REFILL(Q0,J0,Q1,J1,Q2,J2,Q3,J3,CX,CY,CZ,XX,ROW,T)               \
    {   Q0=FLT_MAX;Q1=FLT_MAX;Q2=FLT_MAX;Q3=FLT_MAX;                    \
        J0=-1;J1=-1;J2=-1;J3=-1;                                        \
        for (int j_ = 0; j_ < 64; ++j_) {                               \
            int m_ = (j_ << 6) + lane;                                  \
            bool ex_ = false;                                           \
            for (int e_ = 0; e_ <= T; ++e_) ex_ = ex_ || (s_nbr[ROW][e_] == m_); \
            if (!ex_) {                                                 \
                float mx2 = sc[m_], my2 = sc[m_+NPTS], mz2 = sc[m_+2*NPTS]; \
                float inner = CX*mx2 + CY*my2 + CZ*mz2;                 \
                float mxx2  = mx2*mx2 + my2*my2 + mz2*mz2;              \
                float v = mxx2 - (2.0f * inner - XX);                   \
                int vi = m_;                                            \
                INS_STAGE(Q0,J0) INS_STAGE(Q1,J1) INS_STAGE(Q2,J2) INS_STAGE(Q3,J3) \
            }                                                           \
        }                                                               \
    }

__global__ __launch_bounds__(512, 6)
void lae_kernel(const float* __restrict__ x,
                const float* __restrict__ w1, const float* __restrict__ b1,
                const float* __restrict__ w2, const float* __restrict__ b2,
                const float* __restrict__ w3, const float* __restrict__ b3,
                float* __restrict__ out)
{
    __shared__ float sc[3 * NPTS];        // 48 KB: x | y | z
    __shared__ int   s_nbr[ROWSB][KNN];   // 1.25 KB

    const int tid  = threadIdx.x;
    const int lane = tid & 63;
    const int wid  = tid >> 6;            // 0..7
    const int b    = blockIdx.y;
    const int rA   = blockIdx.x * ROWSB + wid * 2;
    const int rB   = rA + 1;

    // stage batch cloud (layout identical to input: [3][NPTS])
    const float* xb = x + (size_t)b * 3 * NPTS;
    #pragma unroll
    for (int i = tid; i < 3 * NPTS / 4; i += 512)
        ((float4*)sc)[i] = ((const float4*)xb)[i];
    __syncthreads();

    const float cxA = sc[rA], cyA = sc[rA + NPTS], czA = sc[rA + 2*NPTS];
    const float cxB = sc[rB], cyB = sc[rB + NPTS], czB = sc[rB + 2*NPTS];
    const float xxA = cxA*cxA + cyA*cyA + czA*czA;
    const float xxB = cxB*cxB + cyB*cyB + czB*czB;

    // --- pass 1: two independent per-lane sorted top-4 caches, shared loads ---
    float qA0=FLT_MAX,qA1=FLT_MAX,qA2=FLT_MAX,qA3=FLT_MAX;
    int   jA0=-1,jA1=-1,jA2=-1,jA3=-1;
    float qB0=FLT_MAX,qB1=FLT_MAX,qB2=FLT_MAX,qB3=FLT_MAX;
    int   jB0=-1,jB1=-1,jB2=-1,jB3=-1;

    float nx = sc[lane], ny = sc[lane + NPTS], nz = sc[lane + 2*NPTS];
    #pragma unroll 2
    for (int j = 0; j < 64; ++j) {
        const int mi = (j << 6) + lane;
        const float mx = nx, my = ny, mz = nz;
        const int mn = (mi + 64) & (NPTS - 1);
        nx = sc[mn]; ny = sc[mn + NPTS]; nz = sc[mn + 2*NPTS];
        const float mxx = mx*mx + my*my + mz*mz;
        {
            float inner = cxA*mx + cyA*my + czA*mz;
            float v = mxx - (2.0f * inner - xxA);
            int vi = mi;
            INS_STAGE(qA0,jA0) INS_STAGE(qA1,jA1) INS_STAGE(qA2,jA2) INS_STAGE(qA3,jA3)
        }
        {
            float inner = cxB*mx + cyB*my + czB*mz;
            float v = mxx - (2.0f * inner - xxB);
            int vi = mi;
            INS_STAGE(qB0,jB0) INS_STAGE(qB1,jB1) INS_STAGE(qB2,jB2) INS_STAGE(qB3,jB3)
        }
    }

    // --- extraction: 20 x interleaved {wave-min, pop} for rows A and B ---
    int cntA = 4, cntB = 4;
    for (int t = 0; t < KNN; ++t) {
        float gA = wave_min_bcast(qA0);
        float gB = wave_min_bcast(qB0);
        unsigned long long mkA = __ballot(qA0 == gA);
        unsigned long long mkB = __ballot(qB0 == gB);
        int wA = (int)__builtin_ctzll(mkA);
        int wB = (int)__builtin_ctzll(mkB);
        int mA = __builtin_amdgcn_readlane(jA0, wA);
        int mB = __builtin_amdgcn_readlane(jB0, wB);
        if (lane == 0) { s_nbr[wid*2][t] = mA; s_nbr[wid*2+1][t] = mB; }
        if (lane == wA) {
            qA0=qA1; jA0=jA1; qA1=qA2; jA1=jA2; qA2=qA3; jA2=jA3;
            qA3=FLT_MAX; jA3=-1; cntA--;
        }
        if (lane == wB) {
            qB0=qB1; jB0=jB1; qB1=qB2; jB1=jB2; qB2=qB3; jB2=jB3;
            qB3=FLT_MAX; jB3=-1; cntB--;
        }
        if (cntA == 0) { REFILL(qA0,jA0,qA1,jA1,qA2,jA2,qA3,jA3,cxA,cyA,czA,xxA,wid*2,t)   cntA = 4; }
        if (cntB == 0) { REFILL(qB0,jB0,qB1,jB1,qB2,jB2,qB3,jB3,cxB,cyB,czB,xxB,wid*2+1,t) cntB = 4; }
    }

    // --- epilogue: half-wave split (lanes 0-31 = row A, 32-63 = row B) ---
    const int  kh    = lane & 31;
    const bool lower = (lane < 32);
    const float ex = lower ? cxA : cxB;
    const float ey = lower ? cyA : cyB;
    const float ez = lower ? czA : czB;
    const int rowInBlk = wid*2 + (lower ? 0 : 1);
    const int nrow = lower ? rA : rB;

    float sa = b3[0];
    #pragma unroll
    for (int o = 0; o < 16; ++o) {
        float f = b1[o] + w1[o*3+0]*ex + w1[o*3+1]*ey + w1[o*3+2]*ez;
        sa += w3[o] * f;
    }

    const int kk = (kh < KNN) ? kh : 0;
    const int m = s_nbr[rowInBlk][kk];
    float dx = ex - sc[m], dy = ey - sc[m + NPTS], dz = ez - sc[m + 2*NPTS];
    float x1v[16];
    float na = b3[0];
    #pragma unroll
    for (int o = 0; o < 16; ++o) {
        float t2 = b2[o] + w2[o*3+0]*dx + w2[o*3+1]*dy + w2[o*3+2]*dz;
        x1v[o] = t2;
        na += w3[o] * t2;
    }
    float logit = sa + na;
    float l = (logit >= 0.f) ? logit : 0.01f * logit;   // leaky_relu(0.01)
    const bool valid = (kh < KNN);

    float hm  = half_max(valid ? l : -FLT_MAX);
    float lm  = lower ? readlane_f(hm, 31) : readlane_f(hm, 63);
    float p   = valid ? expf(l - lm) : 0.f;
    float hs  = half_sum(p);
    float ps  = lower ? readlane_f(hs, 31) : readlane_f(hs, 63);
    float coef = p / ps;

    float res = 0.f;
    #pragma unroll
    for (int o = 0; o < 16; ++o) {
        float s  = half_sum(coef * x1v[o]);
        float sv = lower ? readlane_f(s, 31) : readlane_f(s, 63);
        res = (kh == o) ? sv : res;
    }
    if (kh < 16) {
        float r = (res > 0.f) ? res : expm1f(res);      // elu
        out[((size_t)b * 16 + kh) * NPTS + nrow] = r;
    }
}

extern "C" void kernel_launch(void* const* d_in, const int* in_sizes, int n_in,
                              void* d_out, int out_size, void* d_ws, size_t ws_size,
                              hipStream_t stream)
{
    const float* x  = (const float*)d_in[0];
    const float* w1 = (const float*)d_in[1];
    const float* b1 = (const float*)d_in[2];
    const float* w2 = (const float*)d_in[3];
    const float* b2 = (const float*)d_in[4];
    const float* w3 = (const float*)d_in[5];
    const float* b3 = (const float*)d_in[6];
    float* out = (float*)d_out;

    dim3 grid(NPTS / ROWSB, 16, 1);
    lae_kernel<<<grid, dim3(512, 1, 1), 0, stream>>>(x, w1, b1, w2, b2, w3, b3, out);
}